// Round 17
// baseline (397.273 us; speedup 1.0000x reference)
//
#include <hip/hip_runtime.h>

// Heat equation, 2 materials, N=512, 499 steps, all frames written.
// Temporal tiling: K=16 steps/launch, 32 dispatches, 1024-thread blocks,
// thread = 1x4 strip (row ty, cols lj0..lj0+3) of a 64x64 halo'd region.
// R17 = DEPTH-2 exchange (R8) under R9's wave-flag protocol (no block
// barrier in the loop). Per PHASE (2 steps): wait fl[w+-1] >= g-1, read
// rows ty+-1, ty+-2 @t from parity buffer (g-1)&1 (4x ds_read_b128),
// locally compute rows ty-1,ty,ty+1 @t+1 then row ty @t+2 (registers),
// publish row ty @t+2 (1x ds_write_b128) + release flag. Halves both the
// cross-wave handshake count and the LDS instruction load vs R9.
// Left/right via DPP 16-lane row shifts (VALU pipe). Frame stores fully
// async (nothing in the loop drains vmcnt).

#define GN 512
#define NSTEPS 499
#define MBND 256
#define INV_DX2 261121.0f     // 511^2 = 1/dx^2
#define DT 5e-7f

#define TO 32                 // owned tile edge
#define KMAX 16               // steps per launch (= trapezoid margin)
#define LOAD 64               // TO + 2*KMAX
#define LSTR 68               // padded LDS row stride (floats)
#define PTS (GN * GN)

// DPP shifts within 16-lane rows. Out-of-range lanes keep their own value
// (bound_ctrl=0, old=src) -> junk only at region-edge columns (outside
// the validity trapezoid).
__device__ __forceinline__ float dpp_row_shr1(float x) {  // lane i <- i-1
    int v = __builtin_amdgcn_update_dpp(__float_as_int(x), __float_as_int(x),
                                        0x111, 0xf, 0xf, false);
    return __int_as_float(v);
}
__device__ __forceinline__ float dpp_row_shl1(float x) {  // lane i <- i+1
    int v = __builtin_amdgcn_update_dpp(__float_as_int(x), __float_as_int(x),
                                        0x101, 0xf, 0xf, false);
    return __int_as_float(v);
}

struct Prm {
    float Ac[4]; bool ifc[4]; bool bcl[4];
    float k1, k2, invk;
    bool aI, aC, aR;
};

// One stencil row update: x = row values, up/dn = vertical neighbors.
__device__ __forceinline__ void srow(const float x[4], const float up[4],
                                     const float dn[4], float out[4],
                                     const Prm& p, bool brF)
{
    const float lf = dpp_row_shr1(x[3]);
    const float rg = dpp_row_shl1(x[0]);
    const float le[4] = {lf, x[0], x[1], x[2]};
    const float ri[4] = {x[1], x[2], x[3], rg};
    #pragma unroll
    for (int j = 0; j < 4; ++j) {
        float v = fmaf(p.Ac[j], fmaf(-4.0f, x[j], (up[j] + dn[j]) + (le[j] + ri[j])), x[j]);
        if (p.aI) v = p.ifc[j] ? (p.k1 * ri[j] + p.k2 * le[j]) * p.invk : v; // OLD nbrs
        if (p.aC) v = p.bcl[j] ? 0.0f : v;
        if (p.aR) v = brF ? 0.0f : v;
        out[j] = v;
    }
}

__device__ __forceinline__ void ld4(float d[4], const float* s) {
    const float4 v = *(const float4*)s;
    d[0] = v.x; d[1] = v.y; d[2] = v.z; d[3] = v.w;
}

template<int STEPS>   // 16 (full) or 3 (tail)
__global__ __launch_bounds__(1024) void heat_multi(
    const float* __restrict__ Tin, float* __restrict__ outBase,
    const float* __restrict__ k1p, const float* __restrict__ k2p,
    const float* __restrict__ a1p, const float* __restrict__ a2p)
{
    __shared__ float Sb[2][LOAD][LSTR];
    __shared__ int fl[16];

    const int t  = threadIdx.x;              // 0..1023
    const int bi = blockIdx.x >> 4;          // 16x16 tile grid
    const int bj = blockIdx.x & 15;
    const int gi0 = bi * TO - KMAX;
    const int gj0 = bj * TO - KMAX;

    const int tx = t & 15, ty = t >> 4;      // 64 rows x 16 col-groups
    const int w  = t >> 6;                   // wave id 0..15 (rows 4w..4w+3)
    const int lj0 = tx * 4;

    // ---- stage region @t0 into Sb[0]; own float4 == (ty,lj0) assignment
    float C[4];
    {
        const bool innerB = (gi0 >= 0) && (gi0 + LOAD <= GN) &&
                            (gj0 >= 0) && (gj0 + LOAD <= GN);
        float4 v;
        if (innerB) {
            v = *(const float4*)&Tin[(size_t)(gi0 + ty) * GN + (gj0 + lj0)];
        } else {
            const int gi_ = gi0 + ty;
            float tmp[4];
            #pragma unroll
            for (int e = 0; e < 4; ++e) {
                const int gj_ = gj0 + lj0 + e;
                tmp[e] = ((unsigned)gi_ < GN && (unsigned)gj_ < GN)
                         ? Tin[(size_t)gi_ * GN + gj_] : 0.0f;
            }
            v = make_float4(tmp[0], tmp[1], tmp[2], tmp[3]);
        }
        *(float4*)&Sb[0][ty][lj0] = v;
        C[0] = v.x; C[1] = v.y; C[2] = v.z; C[3] = v.w;
    }
    if (t < 16) fl[t] = 0;                   // "phase 0 published"
    __syncthreads();                         // the ONLY block-wide barrier

    // clamped neighbor-row indices (junk-safe: outside trapezoid)
    const int rm1 = (ty >= 1) ? ty - 1 : 0;
    const int rm2 = (ty >= 2) ? ty - 2 : 0;
    const int rp1 = (ty <= LOAD - 2) ? ty + 1 : LOAD - 1;
    const int rp2 = (ty <= LOAD - 3) ? ty + 2 : LOAD - 1;
    const int wm = (w > 0) ? w - 1 : 0;      // wait-on-self is always satisfied
    const int wp = (w < 15) ? w + 1 : 15;

    Prm p;
    p.k1 = k1p[0]; p.k2 = k2p[0];
    const float a1 = a1p[0], a2 = a2p[0];
    p.invk = 1.0f / (p.k1 + p.k2);
    #pragma unroll
    for (int j = 0; j < 4; ++j) {
        const int gj_ = gj0 + lj0 + j;
        p.Ac[j]  = (DT * INV_DX2) * ((gj_ < MBND) ? a1 : a2);
        p.ifc[j] = (gj_ == MBND - 1);
        p.bcl[j] = (gj_ <= 0) || (gj_ >= GN - 1);
    }
    p.aI = (bj == 7) || (bj == 8);
    p.aC = (bj == 0) || (bj == 15);
    p.aR = (bi == 0) || (bi == 15);

    const int gi = gi0 + ty;
    const bool brM = (gi - 1 <= 0) || (gi - 1 >= GN - 1);
    const bool br0 = (gi     <= 0) || (gi     >= GN - 1);
    const bool brP = (gi + 1 <= 0) || (gi + 1 >= GN - 1);

    const bool own = (tx >= 4) && (tx < 12) && (ty >= KMAX) && (ty < KMAX + TO);
    float* dst = outBase + ((long)gi * GN + (gj0 + lj0));

    constexpr int NG = STEPS / 2;            // 8 full phases (or 1 for tail)
    #pragma unroll
    for (int g = 1; g <= NG; ++g) {
        // 1) wait for neighbor waves to have published phase g-1
        if (g > 1) {
            while (__atomic_load_n(&fl[wm], __ATOMIC_ACQUIRE) < g - 1 ||
                   __atomic_load_n(&fl[wp], __ATOMIC_ACQUIRE) < g - 1)
                __builtin_amdgcn_s_sleep(1);
        }
        // 2) read 4 ghost rows @ t=2(g-1) from parity buffer (g-1)&1
        const float (*Rb)[LSTR] = Sb[(g - 1) & 1];
        float A[4], B[4], D[4], E[4];
        ld4(A, &Rb[rm2][lj0]);
        ld4(B, &Rb[rm1][lj0]);
        ld4(D, &Rb[rp1][lj0]);
        ld4(E, &Rb[rp2][lj0]);

        // 3) step A (t -> t+1): rows ty-1, ty, ty+1 locally
        float nB[4], nC[4], nD[4];
        srow(B, A, C, nB, p, brM);
        srow(C, B, D, nC, p, br0);
        srow(D, C, E, nD, p, brP);
        if (own) *(float4*)dst = make_float4(nC[0], nC[1], nC[2], nC[3]);
        dst += (long)PTS;

        // 4) step B (t+1 -> t+2): row ty from local neighbors, no LDS
        float n2[4];
        srow(nC, nB, nD, n2, p, br0);
        if (own) *(float4*)dst = make_float4(n2[0], n2[1], n2[2], n2[3]);
        dst += (long)PTS;

        C[0] = n2[0]; C[1] = n2[1]; C[2] = n2[2]; C[3] = n2[3];

        // 5) publish row ty @ t+2 + release flag (orders the ds_write)
        if (g < NG || STEPS == 3) {
            float (*Wb)[LSTR] = Sb[g & 1];
            *(float4*)&Wb[ty][lj0] = make_float4(C[0], C[1], C[2], C[3]);
            if ((t & 63) == 0)
                __atomic_store_n(&fl[w], g, __ATOMIC_RELEASE);
        }
    }

    if constexpr (STEPS == 3) {
        // final odd step: neighbor rows @ t=2 are in Sb[1]; wait phase 1
        while (__atomic_load_n(&fl[wm], __ATOMIC_ACQUIRE) < 1 ||
               __atomic_load_n(&fl[wp], __ATOMIC_ACQUIRE) < 1)
            __builtin_amdgcn_s_sleep(1);
        float B[4], D[4];
        ld4(B, &Sb[1][rm1][lj0]);
        ld4(D, &Sb[1][rp1][lj0]);
        float nC[4];
        srow(C, B, D, nC, p, br0);
        if (own) *(float4*)dst = make_float4(nC[0], nC[1], nC[2], nC[3]);
    }
}

extern "C" void kernel_launch(void* const* d_in, const int* in_sizes, int n_in,
                              void* d_out, int out_size, void* d_ws, size_t ws_size,
                              hipStream_t stream)
{
    const float* u0 = (const float*)d_in[0];
    const float* k1 = (const float*)d_in[1];
    const float* k2 = (const float*)d_in[2];
    const float* a1 = (const float*)d_in[3];
    const float* a2 = (const float*)d_in[4];
    float* out = (float*)d_out;

    const float* src = u0;
    int done = 0;
    while (done < NSTEPS) {
        int steps = NSTEPS - done;
        if (steps > KMAX) steps = KMAX;
        float* ob = out + (size_t)done * PTS;
        if (steps == KMAX)
            heat_multi<KMAX><<<256, 1024, 0, stream>>>(src, ob, k1, k2, a1, a2);
        else  // NSTEPS = 31*16 + 3 -> remainder is always 3
            heat_multi<3><<<256, 1024, 0, stream>>>(src, ob, k1, k2, a1, a2);
        src = ob + (size_t)(steps - 1) * PTS;
        done += steps;
    }
}